// Round 3
// baseline (669.825 us; speedup 1.0000x reference)
//
#include <hip/hip_runtime.h>
#include <hip/hip_bf16.h>

#define B_N 8192
#define M_N 3129
#define M_PAD 3200
#define D_N 512

// ce streaming: each wave owns a contiguous span of 3072 floats (12 float4
// wave-loads). 3072 < 3129 => at most ONE row boundary per span => 2 buckets.
// 8192*3129 floats = 25,632,768 = 8344 spans/array exactly.
#define CE_L 12
#define CE_SPAN (CE_L * 256)     // 3072 floats
#define CE_WPA 8344              // spans per array
#define CE_WTOT (2 * CE_WPA)     // 16688 total spans
#define CE_BLOCKS (CE_WTOT / 4)  // 4172 blocks (4 waves/block)

// Kernel A (prep + zero): normalize g/a, obj rows, zero accumulator region.
#define PREP_G_BLOCKS   (B_N / 4)      // 2048
#define PREP_A_BLOCKS   (M_PAD / 4)    // 800
#define PREP_OBJ_BLOCKS (B_N / 4)      // 2048
#define ZERO_FLOATS (3 * B_N + 8)      // den[8192]|rowsum[16384]|acc[4]|cnt[4]
#define ZERO_BLOCKS 25                 // 25*256*4 = 25600 >= 24584
#define A_BLOCKS (PREP_G_BLOCKS + PREP_A_BLOCKS + PREP_OBJ_BLOCKS + ZERO_BLOCKS)

// Kernel B: 8000 blocks, GEMM at blk%5==2 (1600 tiles exactly). Residency is
// king (R0/R1/R2: BW tracks resident waves linearly), so the GEMM is the
// 16KB single-buffered variant -> 8 blocks/CU (wave-capped) instead of 5/3.
// Other blocks: CE spans (4172), pos (2048), idle tail (180). The final
// reduce+combine is folded in via a last-block arrival counter (saves a node).
#define GEMM_TILES ((M_PAD / 128) * (B_N / 128))   // 25*64 = 1600
#define B_BLOCKS 8000
#define POS_BLOCKS (B_N / 4)                       // 2048

#define GLOBAL_AS __attribute__((address_space(1)))
#define LDS_AS __attribute__((address_space(3)))

typedef __bf16 bf16x8 __attribute__((ext_vector_type(8)));
typedef float f32x4 __attribute__((ext_vector_type(4)));

__device__ __forceinline__ f32x4 nt_load4(const float* p) {
  return __builtin_nontemporal_load((const f32x4*)p);
}

// ---------------------------------------------------------------------------
// One ce span: contiguous 3072 floats, 2 row-buckets split by a wave-uniform
// bound, single end-of-wave shfl reduction, <=2 atomics. Non-temporal loads:
// single-use 205 MB stream must not evict the g/a panels from L3.
// rowsum layout: [0..8191] = logits_q rows, [8192..16383] = logits_rubi.
__device__ __forceinline__ void ce_span(
    int gw, const float* __restrict__ lq, const float* __restrict__ lr,
    float* __restrict__ rowsum) {
  const int lane = threadIdx.x & 63;
  const int aidx = (gw >= CE_WPA) ? 1 : 0;
  const unsigned wl = (unsigned)(gw - aidx * CE_WPA);
  const unsigned f0 = wl * (unsigned)CE_SPAN;          // span start (flat)
  const unsigned r0 = f0 / (unsigned)M_N;              // magic-mul div
  const unsigned b1 = (r0 + 1u) * (unsigned)M_N;       // wave-uniform bound
  const float* base = aidx ? lr : lq;
  const float* p = base + f0 + (unsigned)lane * 4u;

  f32x4 buf[6];
#pragma unroll
  for (int i = 0; i < 6; ++i) buf[i] = nt_load4(p + i * 256);

  float a0 = 0.f, a1 = 0.f;
  const unsigned fbase = f0 + (unsigned)lane * 4u;
#pragma unroll
  for (int i = 0; i < CE_L; ++i) {
    f32x4 v = buf[i % 6];
    if (i + 6 < CE_L) buf[i % 6] = nt_load4(p + (i + 6) * 256);
    unsigned f = fbase + (unsigned)i * 256u;
    float e0 = __expf(v.x), e1 = __expf(v.y), e2 = __expf(v.z), e3 = __expf(v.w);
    float lo = 0.f, hi = 0.f;
    if (f + 0u < b1) lo += e0; else hi += e0;
    if (f + 1u < b1) lo += e1; else hi += e1;
    if (f + 2u < b1) lo += e2; else hi += e2;
    if (f + 3u < b1) lo += e3; else hi += e3;
    a0 += lo; a1 += hi;
  }
  for (int o = 1; o < 64; o <<= 1) {
    a0 += __shfl_xor(a0, o);
    a1 += __shfl_xor(a1, o);
  }
  if (lane == 0) {
    float* rs = rowsum + (aidx ? B_N : 0);
    atomicAdd(rs + r0, a0);
    if (a1 != 0.f) atomicAdd(rs + r0 + 1, a1);  // exact 0 iff no boundary
  }
}

__device__ __forceinline__ void normalize_row(
    const float* __restrict__ x, __bf16* __restrict__ y,
    int row, int nrows_src, int lane) {
  bf16x8 out;
  if (row >= nrows_src) {
    for (int j = 0; j < 8; ++j) out[j] = (__bf16)0.0f;
    *(bf16x8*)(y + (size_t)row * D_N + lane * 8) = out;
    return;
  }
  const float* xr = x + (size_t)row * D_N + lane * 8;
  f32x4 v0 = *(const f32x4*)xr;
  f32x4 v1 = *(const f32x4*)(xr + 4);
  float s = v0.x*v0.x + v0.y*v0.y + v0.z*v0.z + v0.w*v0.w
          + v1.x*v1.x + v1.y*v1.y + v1.z*v1.z + v1.w*v1.w;
  for (int o = 1; o < 64; o <<= 1) s += __shfl_xor(s, o);
  float rn = 1.0f / fmaxf(sqrtf(s), 1e-8f);
  float vals[8] = {v0.x, v0.y, v0.z, v0.w, v1.x, v1.y, v1.z, v1.w};
  for (int j = 0; j < 8; ++j) out[j] = (__bf16)(vals[j] * rn);
  *(bf16x8*)(y + (size_t)row * D_N + lane * 8) = out;
}

// ---------------------------------------------------------------------------
// Kernel A: prep only (normalize g/a, obj) + zero den/rowsum/acc/cnt with
// plain stores (replaces the hipMemsetAsync node).
__global__ __launch_bounds__(256) void a_prep_kernel(
    const float* __restrict__ mm_proj, const float* __restrict__ ans_emb,
    const float* __restrict__ v_max, const float* __restrict__ mm,
    __bf16* __restrict__ g, __bf16* __restrict__ a,
    float* __restrict__ obj, float* __restrict__ zbase) {
  int blk = blockIdx.x;
  int wid = threadIdx.x >> 6, lane = threadIdx.x & 63;
  if (blk < PREP_G_BLOCKS) {
    normalize_row(mm_proj, g, blk * 4 + wid, B_N, lane);
  } else if (blk < PREP_G_BLOCKS + PREP_A_BLOCKS) {
    normalize_row(ans_emb, a, (blk - PREP_G_BLOCKS) * 4 + wid, M_N, lane);
  } else if (blk < PREP_G_BLOCKS + PREP_A_BLOCKS + PREP_OBJ_BLOCKS) {
    int b = (blk - PREP_G_BLOCKS - PREP_A_BLOCKS) * 4 + wid;
    const float* vr = v_max + (size_t)b * D_N + lane * 8;
    const float* mr = mm + (size_t)b * D_N + lane * 8;
    f32x4 a0 = nt_load4(vr), a1 = nt_load4(vr + 4);   // single-use: nt
    f32x4 b0 = nt_load4(mr), b1 = nt_load4(mr + 4);
    float sv = a0.x*a0.x + a0.y*a0.y + a0.z*a0.z + a0.w*a0.w
             + a1.x*a1.x + a1.y*a1.y + a1.z*a1.z + a1.w*a1.w;
    float sm = b0.x*b0.x + b0.y*b0.y + b0.z*b0.z + b0.w*b0.w
             + b1.x*b1.x + b1.y*b1.y + b1.z*b1.z + b1.w*b1.w;
    float sd = a0.x*b0.x + a0.y*b0.y + a0.z*b0.z + a0.w*b0.w
             + a1.x*b1.x + a1.y*b1.y + a1.z*b1.z + a1.w*b1.w;
    for (int o = 1; o < 64; o <<= 1) {
      sv += __shfl_xor(sv, o);
      sm += __shfl_xor(sm, o);
      sd += __shfl_xor(sd, o);
    }
    if (lane == 0) {
      float dist = sd / (fmaxf(sqrtf(sv), 1e-8f) * fmaxf(sqrtf(sm), 1e-8f));
      obj[b] = 1.0f - dist;
    }
  } else {
    int zb = blk - (PREP_G_BLOCKS + PREP_A_BLOCKS + PREP_OBJ_BLOCKS);
    int idx = (zb * 256 + threadIdx.x) * 4;
    if (idx < ZERO_FLOATS) *(f32x4*)(zbase + idx) = f32x4{0.f, 0.f, 0.f, 0.f};
  }
}

// ---------------------------------------------------------------------------
__device__ __forceinline__ void gemm_stage(
    const __bf16* __restrict__ g, const __bf16* __restrict__ a,
    __bf16* As, __bf16* Bs, int t, int brow0, int mrow0, int k0) {
#pragma unroll
  for (int i = 0; i < 2; ++i) {
    int s = t + i * 256;
    int row = s >> 2;
    int kq = (s & 3) << 3;
    const __bf16* ga = g + (size_t)(brow0 + row) * D_N + (k0 + kq);
    __builtin_amdgcn_global_load_lds((const GLOBAL_AS void*)ga,
                                     (LDS_AS void*)(As + s * 8), 16, 0, 0);
    const __bf16* gb = a + (size_t)(mrow0 + row) * D_N + (k0 + kq);
    __builtin_amdgcn_global_load_lds((const GLOBAL_AS void*)gb,
                                     (LDS_AS void*)(Bs + s * 8), 16, 0, 0);
  }
}

// Kernel B: GEMM (16KB single-buffer -> 8 blocks/CU residency) + ALL ce +
// pos, 1-in-5 interleave, final reduce folded in (last-arriving block).
__global__ __launch_bounds__(256) void b_fused_kernel(
    const __bf16* __restrict__ g, const __bf16* __restrict__ a,
    const int* __restrict__ cid,
    const float* __restrict__ mm_proj, const float* __restrict__ ans_emb,
    const float* __restrict__ lq, const float* __restrict__ lr,
    float* __restrict__ den, float* __restrict__ pos,
    float* __restrict__ rowsum, const float* __restrict__ obj,
    float* __restrict__ acc, float* __restrict__ out) {
  __shared__ __bf16 As[128 * 32];
  __shared__ __bf16 Bs[128 * 32];
  __shared__ float fred[4][4];
  __shared__ unsigned s_last;
  const int t = threadIdx.x;
  const int lane = t & 63;
  const int wid = t >> 6;
  const int blk = blockIdx.x;
  const int mod = blk % 5;
  const int d5 = blk / 5;

  if (mod == 2) {
    // ---- GEMM tile role (1600 tiles) ----
    const int tile = d5;
    const int brow0 = (tile / (M_PAD / 128)) * 128;
    const int mrow0 = (tile % (M_PAD / 128)) * 128;
    const int wrow = wid >> 1;      // 0..1
    const int wcol = wid & 1;       // 0..1
    const int r = lane & 15;
    const int quad = lane >> 4;

    f32x4 acc_r[4][4];
    for (int i = 0; i < 4; ++i)
      for (int j = 0; j < 4; ++j)
        acc_r[i][j] = f32x4{0.f, 0.f, 0.f, 0.f};

    for (int k0 = 0; k0 < D_N; k0 += 32) {
      __syncthreads();   // prior-step readers done before overwrite
      gemm_stage(g, a, As, Bs, t, brow0, mrow0, k0);
      __syncthreads();   // implicit vmcnt(0): DMA landed; publish
      bf16x8 af[4], bfr[4];
#pragma unroll
      for (int i = 0; i < 4; ++i)
        af[i] = *(const bf16x8*)(As + (wrow * 64 + i * 16 + r) * 32 + quad * 8);
#pragma unroll
      for (int j = 0; j < 4; ++j)
        bfr[j] = *(const bf16x8*)(Bs + (wcol * 64 + j * 16 + r) * 32 + quad * 8);
#pragma unroll
      for (int i = 0; i < 4; ++i)
#pragma unroll
        for (int j = 0; j < 4; ++j)
          acc_r[i][j] = __builtin_amdgcn_mfma_f32_16x16x32_bf16(
              af[i], bfr[j], acc_r[i][j], 0, 0, 0);
    }

    // C/D layout: col = lane&15, row = quad*4 + reg.
    for (int i = 0; i < 4; ++i) {
      for (int reg = 0; reg < 4; ++reg) {
        float s = 0.0f;
        for (int j = 0; j < 4; ++j) {
          int m = mrow0 + wcol * 64 + j * 16 + r;
          if (m < M_N) s += __expf(acc_r[i][j][reg]);
        }
        s += __shfl_xor(s, 1);
        s += __shfl_xor(s, 2);
        s += __shfl_xor(s, 4);
        s += __shfl_xor(s, 8);
        if (r == 0) {
          int b = brow0 + wrow * 64 + i * 16 + quad * 4 + reg;
          atomicAdd(den + b, s);
        }
      }
    }
  } else {
    // non-GEMM roles: mod in {0,1,3,4} -> local ordinal 0..6399
    const int other = d5 * 4 + mod - (mod > 2 ? 1 : 0);
    if (other < CE_BLOCKS) {
      ce_span(other * 4 + wid, lq, lr, rowsum);
    } else if (other - CE_BLOCKS < POS_BLOCKS) {
      // ---- pos role: recompute both normalized bf16 rows with the EXACT op
      // sequence of normalize_row => bit-identical to the MFMA inputs.
      int b = (other - CE_BLOCKS) * 4 + wid;
      int label = cid[b];
      const float* xr = mm_proj + (size_t)b * D_N + lane * 8;
      f32x4 v0 = *(const f32x4*)xr, v1 = *(const f32x4*)(xr + 4);
      const float* yr = ans_emb + (size_t)label * D_N + lane * 8;
      f32x4 w0 = *(const f32x4*)yr, w1 = *(const f32x4*)(yr + 4);
      float sg = v0.x*v0.x + v0.y*v0.y + v0.z*v0.z + v0.w*v0.w
               + v1.x*v1.x + v1.y*v1.y + v1.z*v1.z + v1.w*v1.w;
      float sa = w0.x*w0.x + w0.y*w0.y + w0.z*w0.z + w0.w*w0.w
               + w1.x*w1.x + w1.y*w1.y + w1.z*w1.z + w1.w*w1.w;
      for (int o = 1; o < 64; o <<= 1) {
        sg += __shfl_xor(sg, o);
        sa += __shfl_xor(sa, o);
      }
      float rng = 1.0f / fmaxf(sqrtf(sg), 1e-8f);
      float rna = 1.0f / fmaxf(sqrtf(sa), 1e-8f);
      float gv[8] = {v0.x, v0.y, v0.z, v0.w, v1.x, v1.y, v1.z, v1.w};
      float av[8] = {w0.x, w0.y, w0.z, w0.w, w1.x, w1.y, w1.z, w1.w};
      float d = 0.0f;
      for (int j = 0; j < 8; ++j)
        d += (float)(__bf16)(gv[j] * rng) * (float)(__bf16)(av[j] * rna);
      for (int o = 1; o < 64; o <<= 1) d += __shfl_xor(d, o);
      if (lane == 0) pos[b] = d;
    }
    // else: idle tail (180 blocks) -> fall through to arrival
  }

  // ---- arrival counter: last block performs the final reduce + combine ----
  __syncthreads();   // per-wave vmcnt(0) drain: this block's stores are in L2
  if (t == 0) {
    __threadfence();  // release
    s_last = (atomicAdd((unsigned*)(acc + 4), 1u) == (unsigned)(B_BLOCKS - 1));
  }
  __syncthreads();
  if (!s_last) return;
  __threadfence();    // acquire side

  // All rowsum/den/pos writes from other blocks are in L2 (plain stores are
  // write-through on CDNA; atomics live in L2). Read them with atomic RMW
  // (adds 0) to bypass any stale L1 line. lq/lr/cid/obj are pre-kernel data.
  float s_nce = 0.f, s_ceq = 0.f, s_cer = 0.f, s_obj = 0.f;
#pragma unroll 4
  for (int jj = 0; jj < 32; ++jj) {
    int b = jj * 256 + t;  // coalesced across threads
    int lab = cid[b];
    float xq = lq[(size_t)b * M_N + lab];
    float xr = lr[(size_t)b * M_N + lab];
    float dn = atomicAdd(den + b, 0.0f);
    float ps = atomicAdd(pos + b, 0.0f);
    float rq = atomicAdd(rowsum + b, 0.0f);
    float rr = atomicAdd(rowsum + B_N + b, 0.0f);
    s_nce += logf(dn) - ps;
    s_ceq += logf(rq) - xq;
    s_cer += logf(rr) - xr;
    s_obj += obj[b];
  }
  for (int o = 1; o < 64; o <<= 1) {
    s_nce += __shfl_xor(s_nce, o);
    s_ceq += __shfl_xor(s_ceq, o);
    s_cer += __shfl_xor(s_cer, o);
    s_obj += __shfl_xor(s_obj, o);
  }
  if (lane == 0) {
    fred[wid][0] = s_nce; fred[wid][1] = s_ceq;
    fred[wid][2] = s_cer; fred[wid][3] = s_obj;
  }
  __syncthreads();
  if (t == 0) {
    float nce = (fred[0][0] + fred[1][0] + fred[2][0] + fred[3][0]) / (float)B_N;
    float ceq = (fred[0][1] + fred[1][1] + fred[2][1] + fred[3][1]) / (float)B_N;
    float cer = (fred[0][2] + fred[1][2] + fred[2][2] + fred[3][2]) / (float)B_N;
    float ob  = (fred[0][3] + fred[1][3] + fred[2][3] + fred[3][3]) / (float)B_N;
    float fusion = (cer + ob + nce) * (1.0f / 3.0f);
    out[0] = fusion + ceq;  // question_loss_weight = 1.0
    out[1] = fusion;
    out[2] = ceq;
  }
}

// ---------------------------------------------------------------------------
extern "C" void kernel_launch(void* const* d_in, const int* in_sizes, int n_in,
                              void* d_out, int out_size, void* d_ws, size_t ws_size,
                              hipStream_t stream) {
  const float* mm_proj     = (const float*)d_in[0];
  const float* ans_emb     = (const float*)d_in[1];
  const float* v_max       = (const float*)d_in[2];
  const float* mm          = (const float*)d_in[3];
  const float* logits_q    = (const float*)d_in[4];
  const float* logits_rubi = (const float*)d_in[5];
  const int*   cid         = (const int*)d_in[6];
  float* out = (float*)d_out;

  // Workspace layout (16B-aligned):
  //   g_bf16 : 8192*512*2 = 8,388,608 B
  //   a_bf16 : 3200*512*2 = 3,276,800 B
  //   zero region: den[8192] | rowsum[16384] | acc[4] | cnt[4]  (kernel A)
  //   pos[8192], obj[8192]
  char* ws = (char*)d_ws;
  __bf16* g = (__bf16*)ws;
  __bf16* a = (__bf16*)(ws + 8388608);
  float* den    = (float*)(ws + 8388608 + 3276800);
  float* rowsum = den + B_N;
  float* acc    = rowsum + 2 * B_N;   // acc[0..3], arrival counter at acc[4]
  float* pos    = acc + 8;
  float* obj    = pos + B_N;

  a_prep_kernel<<<A_BLOCKS, 256, 0, stream>>>(
      mm_proj, ans_emb, v_max, mm, g, a, obj, den);
  b_fused_kernel<<<B_BLOCKS, 256, 0, stream>>>(
      g, a, cid, mm_proj, ans_emb, logits_q, logits_rubi, den, pos, rowsum,
      obj, acc, out);
}

// Round 4
// 306.213 us; speedup vs baseline: 2.1874x; 2.1874x over previous
//
#include <hip/hip_runtime.h>
#include <hip/hip_bf16.h>

#define B_N 8192
#define M_N 3129
#define M_PAD 3200
#define D_N 512

// ce streaming: each wave owns a contiguous span of 3072 floats (12 float4
// wave-loads). 3072 < 3129 => at most ONE row boundary per span => 2 buckets.
// 8192*3129 floats = 25,632,768 = 8344 spans/array exactly.
#define CE_L 12
#define CE_SPAN (CE_L * 256)     // 3072 floats
#define CE_WPA 8344              // spans per array
#define CE_WTOT (2 * CE_WPA)     // 16688 total spans
#define CE_BLOCKS (CE_WTOT / 4)  // 4172 blocks (4 waves/block)

// Kernel A (prep + zero): normalize g/a, obj rows, zero accumulator region.
#define PREP_G_BLOCKS   (B_N / 4)      // 2048
#define PREP_A_BLOCKS   (M_PAD / 4)    // 800
#define PREP_OBJ_BLOCKS (B_N / 4)      // 2048
#define ZERO_FLOATS (3 * B_N + 8)      // den[8192]|rowsum[16384]|acc[4]|cnt[4]
#define ZERO_BLOCKS 25                 // 25*256*4 = 25600 >= 24584
#define A_BLOCKS (PREP_G_BLOCKS + PREP_A_BLOCKS + PREP_OBJ_BLOCKS + ZERO_BLOCKS)

// Kernel B: R1's proven structure (B=86us): 8000 blocks, GEMM at blk%5==2
// (1600 tiles), CE spans on the rest, 32KB double-buffered GEMM. VGPR 72-96
// caps residency at 16 waves/CU = 4 blocks/CU either way, so 32KB LDS is
// free. pos is folded into the GEMM epilogue (the tile owning column cid[b]
// already holds d_logit[b,cid[b]] in its accumulator).
#define GEMM_TILES ((M_PAD / 128) * (B_N / 128))   // 25*64 = 1600
#define B_BLOCKS 8000

#define GLOBAL_AS __attribute__((address_space(1)))
#define LDS_AS __attribute__((address_space(3)))

typedef __bf16 bf16x8 __attribute__((ext_vector_type(8)));
typedef float f32x4 __attribute__((ext_vector_type(4)));

__device__ __forceinline__ f32x4 nt_load4(const float* p) {
  return __builtin_nontemporal_load((const f32x4*)p);
}

// ---------------------------------------------------------------------------
// One ce span: contiguous 3072 floats, 2 row-buckets split by a wave-uniform
// bound, single end-of-wave shfl reduction, <=2 atomics. ALL 12 float4 loads
// issue upfront (R1 had 6 in flight; per-wave BW was latency*outstanding
// limited, so depth 12 ~doubles per-wave streaming BW; +24 VGPR is free
// inside the 65-128 residency band). Non-temporal: single-use 205 MB stream
// must not evict the g/a panels from L3.
// rowsum layout: [0..8191] = logits_q rows, [8192..16383] = logits_rubi.
__device__ __forceinline__ void ce_span(
    int gw, const float* __restrict__ lq, const float* __restrict__ lr,
    float* __restrict__ rowsum) {
  const int lane = threadIdx.x & 63;
  const int aidx = (gw >= CE_WPA) ? 1 : 0;
  const unsigned wl = (unsigned)(gw - aidx * CE_WPA);
  const unsigned f0 = wl * (unsigned)CE_SPAN;          // span start (flat)
  const unsigned r0 = f0 / (unsigned)M_N;              // magic-mul div
  const unsigned b1 = (r0 + 1u) * (unsigned)M_N;       // wave-uniform bound
  const float* base = aidx ? lr : lq;
  const float* p = base + f0 + (unsigned)lane * 4u;

  f32x4 buf[CE_L];
#pragma unroll
  for (int i = 0; i < CE_L; ++i) buf[i] = nt_load4(p + i * 256);

  float a0 = 0.f, a1 = 0.f;
  const unsigned fbase = f0 + (unsigned)lane * 4u;
#pragma unroll
  for (int i = 0; i < CE_L; ++i) {
    f32x4 v = buf[i];
    unsigned f = fbase + (unsigned)i * 256u;
    float e0 = __expf(v.x), e1 = __expf(v.y), e2 = __expf(v.z), e3 = __expf(v.w);
    float lo = 0.f, hi = 0.f;
    if (f + 0u < b1) lo += e0; else hi += e0;
    if (f + 1u < b1) lo += e1; else hi += e1;
    if (f + 2u < b1) lo += e2; else hi += e2;
    if (f + 3u < b1) lo += e3; else hi += e3;
    a0 += lo; a1 += hi;
  }
  for (int o = 1; o < 64; o <<= 1) {
    a0 += __shfl_xor(a0, o);
    a1 += __shfl_xor(a1, o);
  }
  if (lane == 0) {
    float* rs = rowsum + (aidx ? B_N : 0);
    atomicAdd(rs + r0, a0);
    if (a1 != 0.f) atomicAdd(rs + r0 + 1, a1);  // exact 0 iff no boundary
  }
}

__device__ __forceinline__ void normalize_row(
    const float* __restrict__ x, __bf16* __restrict__ y,
    int row, int nrows_src, int lane) {
  bf16x8 out;
  if (row >= nrows_src) {
    for (int j = 0; j < 8; ++j) out[j] = (__bf16)0.0f;
    *(bf16x8*)(y + (size_t)row * D_N + lane * 8) = out;
    return;
  }
  const float* xr = x + (size_t)row * D_N + lane * 8;
  f32x4 v0 = *(const f32x4*)xr;
  f32x4 v1 = *(const f32x4*)(xr + 4);
  float s = v0.x*v0.x + v0.y*v0.y + v0.z*v0.z + v0.w*v0.w
          + v1.x*v1.x + v1.y*v1.y + v1.z*v1.z + v1.w*v1.w;
  for (int o = 1; o < 64; o <<= 1) s += __shfl_xor(s, o);
  float rn = 1.0f / fmaxf(sqrtf(s), 1e-8f);
  float vals[8] = {v0.x, v0.y, v0.z, v0.w, v1.x, v1.y, v1.z, v1.w};
  for (int j = 0; j < 8; ++j) out[j] = (__bf16)(vals[j] * rn);
  *(bf16x8*)(y + (size_t)row * D_N + lane * 8) = out;
}

// ---------------------------------------------------------------------------
// Kernel A: prep only (normalize g/a, obj) + zero den/rowsum/acc/cnt with
// plain stores (replaces the hipMemsetAsync node).
__global__ __launch_bounds__(256) void a_prep_kernel(
    const float* __restrict__ mm_proj, const float* __restrict__ ans_emb,
    const float* __restrict__ v_max, const float* __restrict__ mm,
    __bf16* __restrict__ g, __bf16* __restrict__ a,
    float* __restrict__ obj, float* __restrict__ zbase) {
  int blk = blockIdx.x;
  int wid = threadIdx.x >> 6, lane = threadIdx.x & 63;
  if (blk < PREP_G_BLOCKS) {
    normalize_row(mm_proj, g, blk * 4 + wid, B_N, lane);
  } else if (blk < PREP_G_BLOCKS + PREP_A_BLOCKS) {
    normalize_row(ans_emb, a, (blk - PREP_G_BLOCKS) * 4 + wid, M_N, lane);
  } else if (blk < PREP_G_BLOCKS + PREP_A_BLOCKS + PREP_OBJ_BLOCKS) {
    int b = (blk - PREP_G_BLOCKS - PREP_A_BLOCKS) * 4 + wid;
    const float* vr = v_max + (size_t)b * D_N + lane * 8;
    const float* mr = mm + (size_t)b * D_N + lane * 8;
    f32x4 a0 = nt_load4(vr), a1 = nt_load4(vr + 4);   // single-use: nt
    f32x4 b0 = nt_load4(mr), b1 = nt_load4(mr + 4);
    float sv = a0.x*a0.x + a0.y*a0.y + a0.z*a0.z + a0.w*a0.w
             + a1.x*a1.x + a1.y*a1.y + a1.z*a1.z + a1.w*a1.w;
    float sm = b0.x*b0.x + b0.y*b0.y + b0.z*b0.z + b0.w*b0.w
             + b1.x*b1.x + b1.y*b1.y + b1.z*b1.z + b1.w*b1.w;
    float sd = a0.x*b0.x + a0.y*b0.y + a0.z*b0.z + a0.w*b0.w
             + a1.x*b1.x + a1.y*b1.y + a1.z*b1.z + a1.w*b1.w;
    for (int o = 1; o < 64; o <<= 1) {
      sv += __shfl_xor(sv, o);
      sm += __shfl_xor(sm, o);
      sd += __shfl_xor(sd, o);
    }
    if (lane == 0) {
      float dist = sd / (fmaxf(sqrtf(sv), 1e-8f) * fmaxf(sqrtf(sm), 1e-8f));
      obj[b] = 1.0f - dist;
    }
  } else {
    int zb = blk - (PREP_G_BLOCKS + PREP_A_BLOCKS + PREP_OBJ_BLOCKS);
    int idx = (zb * 256 + threadIdx.x) * 4;
    if (idx < ZERO_FLOATS) *(f32x4*)(zbase + idx) = f32x4{0.f, 0.f, 0.f, 0.f};
  }
}

// ---------------------------------------------------------------------------
__device__ __forceinline__ void gemm_stage(
    const __bf16* __restrict__ g, const __bf16* __restrict__ a,
    __bf16* As, __bf16* Bs, int t, int brow0, int mrow0, int k0) {
#pragma unroll
  for (int i = 0; i < 2; ++i) {
    int s = t + i * 256;
    int row = s >> 2;
    int kq = (s & 3) << 3;
    const __bf16* ga = g + (size_t)(brow0 + row) * D_N + (k0 + kq);
    __builtin_amdgcn_global_load_lds((const GLOBAL_AS void*)ga,
                                     (LDS_AS void*)(As + s * 8), 16, 0, 0);
    const __bf16* gb = a + (size_t)(mrow0 + row) * D_N + (k0 + kq);
    __builtin_amdgcn_global_load_lds((const GLOBAL_AS void*)gb,
                                     (LDS_AS void*)(Bs + s * 8), 16, 0, 0);
  }
}

// Kernel B: GEMM (2-buffer, 1 barrier/K-step; R1's proven loop) + ALL ce,
// role-interleaved 1-in-5. pos folded into GEMM epilogue.
__global__ __launch_bounds__(256) void b_fused_kernel(
    const __bf16* __restrict__ g, const __bf16* __restrict__ a,
    const int* __restrict__ cid,
    const float* __restrict__ lq, const float* __restrict__ lr,
    float* __restrict__ den, float* __restrict__ pos,
    float* __restrict__ rowsum) {
  __shared__ __bf16 As[2][128 * 32];
  __shared__ __bf16 Bs[2][128 * 32];
  const int t = threadIdx.x;
  const int lane = t & 63;
  const int wid = t >> 6;
  const int blk = blockIdx.x;
  const int mod = blk % 5;
  const int d5 = blk / 5;

  if (mod == 2) {
    // ---- GEMM tile role (1600 tiles) ----
    const int tile = d5;
    const int brow0 = (tile / (M_PAD / 128)) * 128;
    const int mrow0 = (tile % (M_PAD / 128)) * 128;
    const int wrow = wid >> 1;      // 0..1
    const int wcol = wid & 1;       // 0..1
    const int r = lane & 15;
    const int quad = lane >> 4;

    f32x4 acc[4][4];
    for (int i = 0; i < 4; ++i)
      for (int j = 0; j < 4; ++j)
        acc[i][j] = f32x4{0.f, 0.f, 0.f, 0.f};

    // prologue: stage K-step 0 into buf 0, drain, barrier
    gemm_stage(g, a, &As[0][0], &Bs[0][0], t, brow0, mrow0, 0);
    int cur = 0;
    __syncthreads();

    for (int ks = 0; ks < D_N / 32; ++ks) {
      // issue next K-step's loads BEFORE consuming current buffer:
      // latency hides under the ds_read+MFMA phase below.
      if (ks + 1 < D_N / 32)
        gemm_stage(g, a, &As[cur ^ 1][0], &Bs[cur ^ 1][0], t, brow0, mrow0,
                   (ks + 1) * 32);
      bf16x8 af[4], bfr[4];
#pragma unroll
      for (int i = 0; i < 4; ++i)
        af[i] = *(const bf16x8*)(&As[cur][(wrow * 64 + i * 16 + r) * 32 + quad * 8]);
#pragma unroll
      for (int j = 0; j < 4; ++j)
        bfr[j] = *(const bf16x8*)(&Bs[cur][(wcol * 64 + j * 16 + r) * 32 + quad * 8]);
#pragma unroll
      for (int i = 0; i < 4; ++i)
#pragma unroll
        for (int j = 0; j < 4; ++j)
          acc[i][j] = __builtin_amdgcn_mfma_f32_16x16x32_bf16(af[i], bfr[j],
                                                              acc[i][j], 0, 0, 0);
      // one barrier per step: drains this step's stage (next buf ready) and
      // guarantees everyone finished reading cur before it's overwritten.
      __syncthreads();
      cur ^= 1;
    }

    // C/D layout: col = lane&15, row = quad*4 + reg.
    // pos fold: the unique (tile,j,r) with m == cid[b] owns d_logit[b,cid[b]]
    // -> plain store, no race. cid is 32KB, L2-resident after first touches.
    for (int i = 0; i < 4; ++i) {
      for (int reg = 0; reg < 4; ++reg) {
        int b = brow0 + wrow * 64 + i * 16 + quad * 4 + reg;
        int lab = cid[b];
        float s = 0.0f;
#pragma unroll
        for (int j = 0; j < 4; ++j) {
          int m = mrow0 + wcol * 64 + j * 16 + r;
          float v = acc[i][j][reg];
          if (m < M_N) s += __expf(v);
          if (m == lab) pos[b] = v;
        }
        s += __shfl_xor(s, 1);
        s += __shfl_xor(s, 2);
        s += __shfl_xor(s, 4);
        s += __shfl_xor(s, 8);
        if (r == 0) atomicAdd(den + b, s);
      }
    }
    return;
  }

  // non-GEMM roles: mod in {0,1,3,4} -> local ordinal 0..6399
  const int other = d5 * 4 + mod - (mod > 2 ? 1 : 0);
  if (other < CE_BLOCKS) {
    ce_span(other * 4 + wid, lq, lr, rowsum);
  }
  // else: idle tail (2228 blocks) retires immediately, freeing slots.
}

// ---------------------------------------------------------------------------
// Kernel C: per-row losses -> acc[0..3], combine folded in via arrival
// counter. Only 32 blocks -> the device-scope fence here is cheap (R1
// measured); NEVER scale this pattern to thousands of blocks (R3 lesson:
// per-block device fences at grid scale collapse memory throughput 5x).
__global__ __launch_bounds__(256) void c_final_kernel(
    const float* __restrict__ den, const float* __restrict__ pos,
    const float* __restrict__ rowsum,
    const float* __restrict__ lq, const float* __restrict__ lr,
    const int* __restrict__ cid, const float* __restrict__ obj,
    float* __restrict__ acc, float* __restrict__ out) {
  int b = blockIdx.x * 256 + threadIdx.x;  // 32*256 == B_N exactly
  int lab = cid[b];
  float xq = lq[(size_t)b * M_N + lab];
  float xr = lr[(size_t)b * M_N + lab];
  float s_nce = logf(den[b]) - pos[b];
  float s_ceq = logf(rowsum[b]) - xq;
  float s_cer = logf(rowsum[B_N + b]) - xr;
  float s_obj = obj[b];
  for (int o = 1; o < 64; o <<= 1) {
    s_nce += __shfl_xor(s_nce, o);
    s_ceq += __shfl_xor(s_ceq, o);
    s_cer += __shfl_xor(s_cer, o);
    s_obj += __shfl_xor(s_obj, o);
  }
  __shared__ float red[4][4];
  int wid = threadIdx.x >> 6;
  if ((threadIdx.x & 63) == 0) {
    red[wid][0] = s_nce; red[wid][1] = s_ceq;
    red[wid][2] = s_cer; red[wid][3] = s_obj;
  }
  __syncthreads();
  if (threadIdx.x < 4) {
    float v = red[0][threadIdx.x] + red[1][threadIdx.x]
            + red[2][threadIdx.x] + red[3][threadIdx.x];
    atomicAdd(acc + threadIdx.x, v);
  }
  if (threadIdx.x == 0) {
    __threadfence();  // release: acc adds (lanes 0-3, same wave) visible first
    unsigned prev = atomicAdd((unsigned*)(acc + 4), 1u);
    if (prev == 31u) {  // last arriver: all 32 blocks' adds are visible
      float nce = atomicAdd(acc + 0, 0.0f) / (float)B_N;
      float ceq = atomicAdd(acc + 1, 0.0f) / (float)B_N;
      float cer = atomicAdd(acc + 2, 0.0f) / (float)B_N;
      float ob  = atomicAdd(acc + 3, 0.0f) / (float)B_N;
      float fusion = (cer + ob + nce) * (1.0f / 3.0f);
      out[0] = fusion + ceq;  // question_loss_weight = 1.0
      out[1] = fusion;
      out[2] = ceq;
    }
  }
}

// ---------------------------------------------------------------------------
extern "C" void kernel_launch(void* const* d_in, const int* in_sizes, int n_in,
                              void* d_out, int out_size, void* d_ws, size_t ws_size,
                              hipStream_t stream) {
  const float* mm_proj     = (const float*)d_in[0];
  const float* ans_emb     = (const float*)d_in[1];
  const float* v_max       = (const float*)d_in[2];
  const float* mm          = (const float*)d_in[3];
  const float* logits_q    = (const float*)d_in[4];
  const float* logits_rubi = (const float*)d_in[5];
  const int*   cid         = (const int*)d_in[6];
  float* out = (float*)d_out;

  // Workspace layout (16B-aligned):
  //   g_bf16 : 8192*512*2 = 8,388,608 B
  //   a_bf16 : 3200*512*2 = 3,276,800 B
  //   zero region: den[8192] | rowsum[16384] | acc[4] | cnt[4]  (kernel A)
  //   pos[8192] (fully written by GEMM epilogue), obj[8192]
  char* ws = (char*)d_ws;
  __bf16* g = (__bf16*)ws;
  __bf16* a = (__bf16*)(ws + 8388608);
  float* den    = (float*)(ws + 8388608 + 3276800);
  float* rowsum = den + B_N;
  float* acc    = rowsum + 2 * B_N;   // acc[0..3], arrival counter at acc[4]
  float* pos    = acc + 8;
  float* obj    = pos + B_N;

  a_prep_kernel<<<A_BLOCKS, 256, 0, stream>>>(
      mm_proj, ans_emb, v_max, mm, g, a, obj, den);
  b_fused_kernel<<<B_BLOCKS, 256, 0, stream>>>(
      g, a, cid, logits_q, logits_rubi, den, pos, rowsum);
  c_final_kernel<<<B_N / 256, 256, 0, stream>>>(
      den, pos, rowsum, logits_q, logits_rubi, cid, obj, acc, out);
}

// Round 5
// 303.227 us; speedup vs baseline: 2.2090x; 1.0098x over previous
//
#include <hip/hip_runtime.h>
#include <hip/hip_bf16.h>

#define B_N 8192
#define M_N 3129
#define M_PAD 3200
#define D_N 512

// ce streaming: each wave owns a contiguous span of 3072 floats (12 float4
// wave-loads). 3072 < 3129 => at most ONE row boundary per span => 2 buckets.
// 8192*3129 floats = 25,632,768 = 8344 spans/array exactly.
#define CE_L 12
#define CE_SPAN (CE_L * 256)     // 3072 floats
#define CE_WPA 8344              // spans per array
#define CE_WTOT (2 * CE_WPA)     // 16688 total spans
#define CE_BLOCKS (CE_WTOT / 4)  // 4172 blocks (4 waves/block)

// Kernel A (prep + zero): normalize g/a, obj rows, zero accumulator region.
#define PREP_G_BLOCKS   (B_N / 4)      // 2048
#define PREP_A_BLOCKS   (M_PAD / 4)    // 800
#define PREP_OBJ_BLOCKS (B_N / 4)      // 2048
#define ZERO_FLOATS (3 * B_N + 8)      // den[8192]|rowsum[16384]|acc[4]|cnt[4]
#define ZERO_BLOCKS 25                 // 25*256*4 = 25600 >= 24584
#define A_BLOCKS (PREP_G_BLOCKS + PREP_A_BLOCKS + PREP_OBJ_BLOCKS + ZERO_BLOCKS)

// Kernel B: 8000 blocks. GEMM at blk%5==2 (1600 tiles), 32KB 2-buf loop
// (R1-proven). CE spread uniformly over the WHOLE range (2-of-3 non-GEMM
// ordinals) so late GEMM tiles always have streaming company (R4 lesson:
// front-loaded CE left the tail GEMM-only and regressed). pos folded into
// the GEMM epilogue. GEMM tiles are XCD-GROUPED: blk%8 is this block's XCD;
// XCD x owns tiles [x*200,(x+1)*200) = 8 full brow-panels, so each g panel
// is fetched from L3 once TOTAL and reused 25x from that XCD's private L2
// (un-grouped, every XCD re-fetched every panel; ~410 MB of fabric traffic).
#define GEMM_TILES ((M_PAD / 128) * (B_N / 128))   // 25*64 = 1600
#define B_BLOCKS 8000

#define GLOBAL_AS __attribute__((address_space(1)))
#define LDS_AS __attribute__((address_space(3)))

typedef __bf16 bf16x8 __attribute__((ext_vector_type(8)));
typedef float f32x4 __attribute__((ext_vector_type(4)));

__device__ __forceinline__ f32x4 nt_load4(const float* p) {
  return __builtin_nontemporal_load((const f32x4*)p);
}

// ---------------------------------------------------------------------------
// One ce span (R1-proven 6-deep rolling prefetch — the 12-upfront variant
// coincided with R4's regression and is reverted per rigor rules).
// Non-temporal: single-use 205 MB stream must not evict g/a from L2/L3.
// rowsum layout: [0..8191] = logits_q rows, [8192..16383] = logits_rubi.
__device__ __forceinline__ void ce_span(
    int gw, const float* __restrict__ lq, const float* __restrict__ lr,
    float* __restrict__ rowsum) {
  const int lane = threadIdx.x & 63;
  const int aidx = (gw >= CE_WPA) ? 1 : 0;
  const unsigned wl = (unsigned)(gw - aidx * CE_WPA);
  const unsigned f0 = wl * (unsigned)CE_SPAN;          // span start (flat)
  const unsigned r0 = f0 / (unsigned)M_N;              // magic-mul div
  const unsigned b1 = (r0 + 1u) * (unsigned)M_N;       // wave-uniform bound
  const float* base = aidx ? lr : lq;
  const float* p = base + f0 + (unsigned)lane * 4u;

  f32x4 buf[6];
#pragma unroll
  for (int i = 0; i < 6; ++i) buf[i] = nt_load4(p + i * 256);

  float a0 = 0.f, a1 = 0.f;
  const unsigned fbase = f0 + (unsigned)lane * 4u;
#pragma unroll
  for (int i = 0; i < CE_L; ++i) {
    f32x4 v = buf[i % 6];
    if (i + 6 < CE_L) buf[i % 6] = nt_load4(p + (i + 6) * 256);
    unsigned f = fbase + (unsigned)i * 256u;
    float e0 = __expf(v.x), e1 = __expf(v.y), e2 = __expf(v.z), e3 = __expf(v.w);
    float lo = 0.f, hi = 0.f;
    if (f + 0u < b1) lo += e0; else hi += e0;
    if (f + 1u < b1) lo += e1; else hi += e1;
    if (f + 2u < b1) lo += e2; else hi += e2;
    if (f + 3u < b1) lo += e3; else hi += e3;
    a0 += lo; a1 += hi;
  }
  for (int o = 1; o < 64; o <<= 1) {
    a0 += __shfl_xor(a0, o);
    a1 += __shfl_xor(a1, o);
  }
  if (lane == 0) {
    float* rs = rowsum + (aidx ? B_N : 0);
    atomicAdd(rs + r0, a0);
    if (a1 != 0.f) atomicAdd(rs + r0 + 1, a1);  // exact 0 iff no boundary
  }
}

__device__ __forceinline__ void normalize_row(
    const float* __restrict__ x, __bf16* __restrict__ y,
    int row, int nrows_src, int lane) {
  bf16x8 out;
  if (row >= nrows_src) {
    for (int j = 0; j < 8; ++j) out[j] = (__bf16)0.0f;
    *(bf16x8*)(y + (size_t)row * D_N + lane * 8) = out;
    return;
  }
  const float* xr = x + (size_t)row * D_N + lane * 8;
  f32x4 v0 = *(const f32x4*)xr;
  f32x4 v1 = *(const f32x4*)(xr + 4);
  float s = v0.x*v0.x + v0.y*v0.y + v0.z*v0.z + v0.w*v0.w
          + v1.x*v1.x + v1.y*v1.y + v1.z*v1.z + v1.w*v1.w;
  for (int o = 1; o < 64; o <<= 1) s += __shfl_xor(s, o);
  float rn = 1.0f / fmaxf(sqrtf(s), 1e-8f);
  float vals[8] = {v0.x, v0.y, v0.z, v0.w, v1.x, v1.y, v1.z, v1.w};
  for (int j = 0; j < 8; ++j) out[j] = (__bf16)(vals[j] * rn);
  *(bf16x8*)(y + (size_t)row * D_N + lane * 8) = out;
}

// ---------------------------------------------------------------------------
// Kernel A: prep only (normalize g/a, obj) + zero den/rowsum/acc/cnt with
// plain stores (replaces the hipMemsetAsync node).
__global__ __launch_bounds__(256) void a_prep_kernel(
    const float* __restrict__ mm_proj, const float* __restrict__ ans_emb,
    const float* __restrict__ v_max, const float* __restrict__ mm,
    __bf16* __restrict__ g, __bf16* __restrict__ a,
    float* __restrict__ obj, float* __restrict__ zbase) {
  int blk = blockIdx.x;
  int wid = threadIdx.x >> 6, lane = threadIdx.x & 63;
  if (blk < PREP_G_BLOCKS) {
    normalize_row(mm_proj, g, blk * 4 + wid, B_N, lane);
  } else if (blk < PREP_G_BLOCKS + PREP_A_BLOCKS) {
    normalize_row(ans_emb, a, (blk - PREP_G_BLOCKS) * 4 + wid, M_N, lane);
  } else if (blk < PREP_G_BLOCKS + PREP_A_BLOCKS + PREP_OBJ_BLOCKS) {
    int b = (blk - PREP_G_BLOCKS - PREP_A_BLOCKS) * 4 + wid;
    const float* vr = v_max + (size_t)b * D_N + lane * 8;
    const float* mr = mm + (size_t)b * D_N + lane * 8;
    f32x4 a0 = nt_load4(vr), a1 = nt_load4(vr + 4);   // single-use: nt
    f32x4 b0 = nt_load4(mr), b1 = nt_load4(mr + 4);
    float sv = a0.x*a0.x + a0.y*a0.y + a0.z*a0.z + a0.w*a0.w
             + a1.x*a1.x + a1.y*a1.y + a1.z*a1.z + a1.w*a1.w;
    float sm = b0.x*b0.x + b0.y*b0.y + b0.z*b0.z + b0.w*b0.w
             + b1.x*b1.x + b1.y*b1.y + b1.z*b1.z + b1.w*b1.w;
    float sd = a0.x*b0.x + a0.y*b0.y + a0.z*b0.z + a0.w*b0.w
             + a1.x*b1.x + a1.y*b1.y + a1.z*b1.z + a1.w*b1.w;
    for (int o = 1; o < 64; o <<= 1) {
      sv += __shfl_xor(sv, o);
      sm += __shfl_xor(sm, o);
      sd += __shfl_xor(sd, o);
    }
    if (lane == 0) {
      float dist = sd / (fmaxf(sqrtf(sv), 1e-8f) * fmaxf(sqrtf(sm), 1e-8f));
      obj[b] = 1.0f - dist;
    }
  } else {
    int zb = blk - (PREP_G_BLOCKS + PREP_A_BLOCKS + PREP_OBJ_BLOCKS);
    int idx = (zb * 256 + threadIdx.x) * 4;
    if (idx < ZERO_FLOATS) *(f32x4*)(zbase + idx) = f32x4{0.f, 0.f, 0.f, 0.f};
  }
}

// ---------------------------------------------------------------------------
__device__ __forceinline__ void gemm_stage(
    const __bf16* __restrict__ g, const __bf16* __restrict__ a,
    __bf16* As, __bf16* Bs, int t, int brow0, int mrow0, int k0) {
#pragma unroll
  for (int i = 0; i < 2; ++i) {
    int s = t + i * 256;
    int row = s >> 2;
    int kq = (s & 3) << 3;
    const __bf16* ga = g + (size_t)(brow0 + row) * D_N + (k0 + kq);
    __builtin_amdgcn_global_load_lds((const GLOBAL_AS void*)ga,
                                     (LDS_AS void*)(As + s * 8), 16, 0, 0);
    const __bf16* gb = a + (size_t)(mrow0 + row) * D_N + (k0 + kq);
    __builtin_amdgcn_global_load_lds((const GLOBAL_AS void*)gb,
                                     (LDS_AS void*)(Bs + s * 8), 16, 0, 0);
  }
}

// Kernel B: GEMM (2-buffer, 1 barrier/K-step; R1's proven loop, XCD-grouped
// tiles) + ALL ce (spread across full range), pos folded into epilogue.
__global__ __launch_bounds__(256) void b_fused_kernel(
    const __bf16* __restrict__ g, const __bf16* __restrict__ a,
    const int* __restrict__ cid,
    const float* __restrict__ lq, const float* __restrict__ lr,
    float* __restrict__ den, float* __restrict__ pos,
    float* __restrict__ rowsum) {
  __shared__ __bf16 As[2][128 * 32];
  __shared__ __bf16 Bs[2][128 * 32];
  const int t = threadIdx.x;
  const int lane = t & 63;
  const int wid = t >> 6;
  const int blk = blockIdx.x;
  const int mod = blk % 5;
  const int d5 = blk / 5;

  if (mod == 2) {
    // ---- GEMM tile role (1600 tiles), XCD-grouped mapping ----
    // This block's XCD = blk%8 (round-robin dispatch heuristic; a wrong
    // mapping only costs locality, never correctness). Among GEMM blocks,
    // each XCD appears once per 8 consecutive d5 -> rank r = d5/8 in [0,200).
    // XCD x owns tiles [x*200, (x+1)*200) = brows [x*8, x*8+8) x all mrows:
    // 25 consecutive-in-time tiles share one 128KB g panel (L2-hit reuse),
    // and each g panel is fetched from L3 exactly once chip-wide.
    const int xcd = blk & 7;
    const int tile = xcd * (GEMM_TILES / 8) + (d5 >> 3);
    const int brow0 = (tile / (M_PAD / 128)) * 128;
    const int mrow0 = (tile % (M_PAD / 128)) * 128;
    const int wrow = wid >> 1;      // 0..1
    const int wcol = wid & 1;       // 0..1
    const int r = lane & 15;
    const int quad = lane >> 4;

    f32x4 acc[4][4];
    for (int i = 0; i < 4; ++i)
      for (int j = 0; j < 4; ++j)
        acc[i][j] = f32x4{0.f, 0.f, 0.f, 0.f};

    // prologue: stage K-step 0 into buf 0, drain, barrier
    gemm_stage(g, a, &As[0][0], &Bs[0][0], t, brow0, mrow0, 0);
    int cur = 0;
    __syncthreads();

    for (int ks = 0; ks < D_N / 32; ++ks) {
      // issue next K-step's loads BEFORE consuming current buffer:
      // latency hides under the ds_read+MFMA phase below.
      if (ks + 1 < D_N / 32)
        gemm_stage(g, a, &As[cur ^ 1][0], &Bs[cur ^ 1][0], t, brow0, mrow0,
                   (ks + 1) * 32);
      bf16x8 af[4], bfr[4];
#pragma unroll
      for (int i = 0; i < 4; ++i)
        af[i] = *(const bf16x8*)(&As[cur][(wrow * 64 + i * 16 + r) * 32 + quad * 8]);
#pragma unroll
      for (int j = 0; j < 4; ++j)
        bfr[j] = *(const bf16x8*)(&Bs[cur][(wcol * 64 + j * 16 + r) * 32 + quad * 8]);
#pragma unroll
      for (int i = 0; i < 4; ++i)
#pragma unroll
        for (int j = 0; j < 4; ++j)
          acc[i][j] = __builtin_amdgcn_mfma_f32_16x16x32_bf16(af[i], bfr[j],
                                                              acc[i][j], 0, 0, 0);
      // one barrier per step: drains this step's stage (next buf ready) and
      // guarantees everyone finished reading cur before it's overwritten.
      __syncthreads();
      cur ^= 1;
    }

    // C/D layout: col = lane&15, row = quad*4 + reg.
    // pos fold: the unique (tile,j,r) with m == cid[b] owns d_logit[b,cid[b]]
    // -> plain store, no race. cid is 32KB, L2-resident after first touches.
    for (int i = 0; i < 4; ++i) {
      for (int reg = 0; reg < 4; ++reg) {
        int b = brow0 + wrow * 64 + i * 16 + quad * 4 + reg;
        int lab = cid[b];
        float s = 0.0f;
#pragma unroll
        for (int j = 0; j < 4; ++j) {
          int m = mrow0 + wcol * 64 + j * 16 + r;
          float v = acc[i][j][reg];
          if (m < M_N) s += __expf(v);
          if (m == lab) pos[b] = v;
        }
        s += __shfl_xor(s, 1);
        s += __shfl_xor(s, 2);
        s += __shfl_xor(s, 4);
        s += __shfl_xor(s, 8);
        if (r == 0) atomicAdd(den + b, s);
      }
    }
    return;
  }

  // non-GEMM roles: mod in {0,1,3,4} -> ordinal 0..6399, uniform over the
  // grid. CE takes 2-of-3 ordinals (4268 slots >= 4172 needed) so streaming
  // blocks accompany the GEMM all the way to the last tile (R4 tail lesson).
  const int other = d5 * 4 + mod - (mod > 2 ? 1 : 0);
  const int om = other % 3;
  if (om != 2) {
    const int ce_idx = (other / 3) * 2 + om;   // bijective onto [0,4268)
    if (ce_idx < CE_BLOCKS) ce_span(ce_idx * 4 + wid, lq, lr, rowsum);
  }
  // om==2 and overflow ordinals: idle, retire immediately.
}

// ---------------------------------------------------------------------------
// Kernel C: per-row losses -> acc[0..3], combine folded in via arrival
// counter. Only 32 blocks -> the device-scope fence here is cheap (R1
// measured); NEVER scale this pattern to thousands of blocks (R3 lesson:
// per-block device fences at grid scale collapse memory throughput 5x).
__global__ __launch_bounds__(256) void c_final_kernel(
    const float* __restrict__ den, const float* __restrict__ pos,
    const float* __restrict__ rowsum,
    const float* __restrict__ lq, const float* __restrict__ lr,
    const int* __restrict__ cid, const float* __restrict__ obj,
    float* __restrict__ acc, float* __restrict__ out) {
  int b = blockIdx.x * 256 + threadIdx.x;  // 32*256 == B_N exactly
  int lab = cid[b];
  float xq = lq[(size_t)b * M_N + lab];
  float xr = lr[(size_t)b * M_N + lab];
  float s_nce = logf(den[b]) - pos[b];
  float s_ceq = logf(rowsum[b]) - xq;
  float s_cer = logf(rowsum[B_N + b]) - xr;
  float s_obj = obj[b];
  for (int o = 1; o < 64; o <<= 1) {
    s_nce += __shfl_xor(s_nce, o);
    s_ceq += __shfl_xor(s_ceq, o);
    s_cer += __shfl_xor(s_cer, o);
    s_obj += __shfl_xor(s_obj, o);
  }
  __shared__ float red[4][4];
  int wid = threadIdx.x >> 6;
  if ((threadIdx.x & 63) == 0) {
    red[wid][0] = s_nce; red[wid][1] = s_ceq;
    red[wid][2] = s_cer; red[wid][3] = s_obj;
  }
  __syncthreads();
  if (threadIdx.x < 4) {
    float v = red[0][threadIdx.x] + red[1][threadIdx.x]
            + red[2][threadIdx.x] + red[3][threadIdx.x];
    atomicAdd(acc + threadIdx.x, v);
  }
  if (threadIdx.x == 0) {
    __threadfence();  // release: acc adds (lanes 0-3, same wave) visible first
    unsigned prev = atomicAdd((unsigned*)(acc + 4), 1u);
    if (prev == 31u) {  // last arriver: all 32 blocks' adds are visible
      float nce = atomicAdd(acc + 0, 0.0f) / (float)B_N;
      float ceq = atomicAdd(acc + 1, 0.0f) / (float)B_N;
      float cer = atomicAdd(acc + 2, 0.0f) / (float)B_N;
      float ob  = atomicAdd(acc + 3, 0.0f) / (float)B_N;
      float fusion = (cer + ob + nce) * (1.0f / 3.0f);
      out[0] = fusion + ceq;  // question_loss_weight = 1.0
      out[1] = fusion;
      out[2] = ceq;
    }
  }
}

// ---------------------------------------------------------------------------
extern "C" void kernel_launch(void* const* d_in, const int* in_sizes, int n_in,
                              void* d_out, int out_size, void* d_ws, size_t ws_size,
                              hipStream_t stream) {
  const float* mm_proj     = (const float*)d_in[0];
  const float* ans_emb     = (const float*)d_in[1];
  const float* v_max       = (const float*)d_in[2];
  const float* mm          = (const float*)d_in[3];
  const float* logits_q    = (const float*)d_in[4];
  const float* logits_rubi = (const float*)d_in[5];
  const int*   cid         = (const int*)d_in[6];
  float* out = (float*)d_out;

  // Workspace layout (16B-aligned):
  //   g_bf16 : 8192*512*2 = 8,388,608 B
  //   a_bf16 : 3200*512*2 = 3,276,800 B
  //   zero region: den[8192] | rowsum[16384] | acc[4] | cnt[4]  (kernel A)
  //   pos[8192] (fully written by GEMM epilogue), obj[8192]
  char* ws = (char*)d_ws;
  __bf16* g = (__bf16*)ws;
  __bf16* a = (__bf16*)(ws + 8388608);
  float* den    = (float*)(ws + 8388608 + 3276800);
  float* rowsum = den + B_N;
  float* acc    = rowsum + 2 * B_N;   // acc[0..3], arrival counter at acc[4]
  float* pos    = acc + 8;
  float* obj    = pos + B_N;

  a_prep_kernel<<<A_BLOCKS, 256, 0, stream>>>(
      mm_proj, ans_emb, v_max, mm, g, a, obj, den);
  b_fused_kernel<<<B_BLOCKS, 256, 0, stream>>>(
      g, a, cid, logits_q, logits_rubi, den, pos, rowsum);
  c_final_kernel<<<B_N / 256, 256, 0, stream>>>(
      den, pos, rowsum, logits_q, logits_rubi, cid, obj, acc, out);
}

// Round 6
// 300.182 us; speedup vs baseline: 2.2314x; 1.0101x over previous
//
#include <hip/hip_runtime.h>
#include <hip/hip_bf16.h>

#define B_N 8192
#define M_N 3129
#define M_PAD 3200
#define D_N 512

// ce streaming: each wave owns a contiguous span of 3072 floats (12 float4
// wave-loads). 3072 < 3129 => at most ONE row boundary per span => 2 buckets.
// 8192*3129 floats = 25,632,768 = 8344 spans/array exactly.
#define CE_L 12
#define CE_SPAN (CE_L * 256)     // 3072 floats
#define CE_WPA 8344              // spans per array
#define CE_WTOT (2 * CE_WPA)     // 16688 total spans
#define CE_BLOCKS (CE_WTOT / 4)  // 4172 blocks (4 waves/block)

// Kernel A (prep + zero): normalize g/a + zero accumulators. obj moved to B.
#define PREP_G_BLOCKS   (B_N / 4)      // 2048
#define PREP_A_BLOCKS   (M_PAD / 4)    // 800
#define ZERO_FLOATS (3 * B_N + 8)      // den[8192]|rowsum[16384]|acc[4]|cnt[4]
#define ZERO_BLOCKS 25                 // 25*256*4 = 25600 >= 24584
#define A_BLOCKS (PREP_G_BLOCKS + PREP_A_BLOCKS + ZERO_BLOCKS)   // 2873

// Kernel B: PHASE-SEPARATED (R5 lesson: interleaving caps the GEMM at its
// slot share; GEMM rate ~= 1.1 TF per resident GEMM block, and 1-in-5 gave
// 282 TF = the whole 95us). Blocks 0..1599 = GEMM: dispatcher fills every CU
// with 5 GEMM blocks (32KB LDS cap) -> dense phase at multi-block/CU rate
// (m97 ladder: ~3.4 TF/CU at >=3 blocks/CU) while HBM is quiet (g+a panels
// are L2-resident per XCD). CE blocks then backfill as GEMM retires and
// stream at full BW with 20 waves/CU. obj (2048 blocks) fills the tail.
#define GEMM_TILES ((M_PAD / 128) * (B_N / 128))   // 25*64 = 1600
#define B_BLOCKS 8000
#define OBJ_BLOCKS (B_N / 4)                       // 2048

#define GLOBAL_AS __attribute__((address_space(1)))
#define LDS_AS __attribute__((address_space(3)))

typedef __bf16 bf16x8 __attribute__((ext_vector_type(8)));
typedef float f32x4 __attribute__((ext_vector_type(4)));

__device__ __forceinline__ f32x4 nt_load4(const float* p) {
  return __builtin_nontemporal_load((const f32x4*)p);
}

// ---------------------------------------------------------------------------
// One ce span (R1-proven 6-deep rolling prefetch). Non-temporal: single-use
// 205 MB stream must not evict g/a or L3-resident logits prematurely.
// rowsum layout: [0..8191] = logits_q rows, [8192..16383] = logits_rubi.
__device__ __forceinline__ void ce_span(
    int gw, const float* __restrict__ lq, const float* __restrict__ lr,
    float* __restrict__ rowsum) {
  const int lane = threadIdx.x & 63;
  const int aidx = (gw >= CE_WPA) ? 1 : 0;
  const unsigned wl = (unsigned)(gw - aidx * CE_WPA);
  const unsigned f0 = wl * (unsigned)CE_SPAN;          // span start (flat)
  const unsigned r0 = f0 / (unsigned)M_N;              // magic-mul div
  const unsigned b1 = (r0 + 1u) * (unsigned)M_N;       // wave-uniform bound
  const float* base = aidx ? lr : lq;
  const float* p = base + f0 + (unsigned)lane * 4u;

  f32x4 buf[6];
#pragma unroll
  for (int i = 0; i < 6; ++i) buf[i] = nt_load4(p + i * 256);

  float a0 = 0.f, a1 = 0.f;
  const unsigned fbase = f0 + (unsigned)lane * 4u;
#pragma unroll
  for (int i = 0; i < CE_L; ++i) {
    f32x4 v = buf[i % 6];
    if (i + 6 < CE_L) buf[i % 6] = nt_load4(p + (i + 6) * 256);
    unsigned f = fbase + (unsigned)i * 256u;
    float e0 = __expf(v.x), e1 = __expf(v.y), e2 = __expf(v.z), e3 = __expf(v.w);
    float lo = 0.f, hi = 0.f;
    if (f + 0u < b1) lo += e0; else hi += e0;
    if (f + 1u < b1) lo += e1; else hi += e1;
    if (f + 2u < b1) lo += e2; else hi += e2;
    if (f + 3u < b1) lo += e3; else hi += e3;
    a0 += lo; a1 += hi;
  }
  for (int o = 1; o < 64; o <<= 1) {
    a0 += __shfl_xor(a0, o);
    a1 += __shfl_xor(a1, o);
  }
  if (lane == 0) {
    float* rs = rowsum + (aidx ? B_N : 0);
    atomicAdd(rs + r0, a0);
    if (a1 != 0.f) atomicAdd(rs + r0 + 1, a1);  // exact 0 iff no boundary
  }
}

__device__ __forceinline__ void normalize_row(
    const float* __restrict__ x, __bf16* __restrict__ y,
    int row, int nrows_src, int lane) {
  bf16x8 out;
  if (row >= nrows_src) {
    for (int j = 0; j < 8; ++j) out[j] = (__bf16)0.0f;
    *(bf16x8*)(y + (size_t)row * D_N + lane * 8) = out;
    return;
  }
  const float* xr = x + (size_t)row * D_N + lane * 8;
  f32x4 v0 = *(const f32x4*)xr;
  f32x4 v1 = *(const f32x4*)(xr + 4);
  float s = v0.x*v0.x + v0.y*v0.y + v0.z*v0.z + v0.w*v0.w
          + v1.x*v1.x + v1.y*v1.y + v1.z*v1.z + v1.w*v1.w;
  for (int o = 1; o < 64; o <<= 1) s += __shfl_xor(s, o);
  float rn = 1.0f / fmaxf(sqrtf(s), 1e-8f);
  float vals[8] = {v0.x, v0.y, v0.z, v0.w, v1.x, v1.y, v1.z, v1.w};
  for (int j = 0; j < 8; ++j) out[j] = (__bf16)(vals[j] * rn);
  *(bf16x8*)(y + (size_t)row * D_N + lane * 8) = out;
}

// ---------------------------------------------------------------------------
// Kernel A: normalize g/a + zero den/rowsum/acc/cnt. ~22 MB -> ~10 us.
__global__ __launch_bounds__(256) void a_prep_kernel(
    const float* __restrict__ mm_proj, const float* __restrict__ ans_emb,
    __bf16* __restrict__ g, __bf16* __restrict__ a,
    float* __restrict__ zbase) {
  int blk = blockIdx.x;
  int wid = threadIdx.x >> 6, lane = threadIdx.x & 63;
  if (blk < PREP_G_BLOCKS) {
    normalize_row(mm_proj, g, blk * 4 + wid, B_N, lane);
  } else if (blk < PREP_G_BLOCKS + PREP_A_BLOCKS) {
    normalize_row(ans_emb, a, (blk - PREP_G_BLOCKS) * 4 + wid, M_N, lane);
  } else {
    int zb = blk - (PREP_G_BLOCKS + PREP_A_BLOCKS);
    int idx = (zb * 256 + threadIdx.x) * 4;
    if (idx < ZERO_FLOATS) *(f32x4*)(zbase + idx) = f32x4{0.f, 0.f, 0.f, 0.f};
  }
}

// ---------------------------------------------------------------------------
__device__ __forceinline__ void gemm_stage(
    const __bf16* __restrict__ g, const __bf16* __restrict__ a,
    __bf16* As, __bf16* Bs, int t, int brow0, int mrow0, int k0) {
#pragma unroll
  for (int i = 0; i < 2; ++i) {
    int s = t + i * 256;
    int row = s >> 2;
    int kq = (s & 3) << 3;
    const __bf16* ga = g + (size_t)(brow0 + row) * D_N + (k0 + kq);
    __builtin_amdgcn_global_load_lds((const GLOBAL_AS void*)ga,
                                     (LDS_AS void*)(As + s * 8), 16, 0, 0);
    const __bf16* gb = a + (size_t)(mrow0 + row) * D_N + (k0 + kq);
    __builtin_amdgcn_global_load_lds((const GLOBAL_AS void*)gb,
                                     (LDS_AS void*)(Bs + s * 8), 16, 0, 0);
  }
}

// Kernel B: dense-GEMM phase (blocks 0..1599, XCD-grouped, 2-buf loop, pos
// folded) -> CE phase (4172 blocks) -> obj phase (2048 blocks).
__global__ __launch_bounds__(256) void b_fused_kernel(
    const __bf16* __restrict__ g, const __bf16* __restrict__ a,
    const int* __restrict__ cid,
    const float* __restrict__ v_max, const float* __restrict__ mm,
    const float* __restrict__ lq, const float* __restrict__ lr,
    float* __restrict__ den, float* __restrict__ pos,
    float* __restrict__ rowsum, float* __restrict__ obj) {
  __shared__ __bf16 As[2][128 * 32];
  __shared__ __bf16 Bs[2][128 * 32];
  const int t = threadIdx.x;
  const int lane = t & 63;
  const int wid = t >> 6;
  const int blk = blockIdx.x;

  if (blk < GEMM_TILES) {
    // ---- GEMM tile role, XCD-grouped mapping (kept from R5: FETCH -61MB).
    // blk%8 ~ XCD (round-robin dispatch heuristic; wrong mapping only costs
    // locality). XCD x owns tiles [x*200,(x+1)*200) = brows [x*8,x*8+8):
    // each 128KB g panel is fetched from L3 once chip-wide, reused 25x in L2.
    const int xcd = blk & 7;
    const int tile = xcd * (GEMM_TILES / 8) + (blk >> 3);
    const int brow0 = (tile / (M_PAD / 128)) * 128;
    const int mrow0 = (tile % (M_PAD / 128)) * 128;
    const int wrow = wid >> 1;      // 0..1
    const int wcol = wid & 1;       // 0..1
    const int r = lane & 15;
    const int quad = lane >> 4;

    f32x4 acc[4][4];
    for (int i = 0; i < 4; ++i)
      for (int j = 0; j < 4; ++j)
        acc[i][j] = f32x4{0.f, 0.f, 0.f, 0.f};

    // prologue: stage K-step 0 into buf 0, drain, barrier
    gemm_stage(g, a, &As[0][0], &Bs[0][0], t, brow0, mrow0, 0);
    int cur = 0;
    __syncthreads();

    for (int ks = 0; ks < D_N / 32; ++ks) {
      // issue next K-step's loads BEFORE consuming current buffer:
      // latency hides under the ds_read+MFMA phase below.
      if (ks + 1 < D_N / 32)
        gemm_stage(g, a, &As[cur ^ 1][0], &Bs[cur ^ 1][0], t, brow0, mrow0,
                   (ks + 1) * 32);
      bf16x8 af[4], bfr[4];
#pragma unroll
      for (int i = 0; i < 4; ++i)
        af[i] = *(const bf16x8*)(&As[cur][(wrow * 64 + i * 16 + r) * 32 + quad * 8]);
#pragma unroll
      for (int j = 0; j < 4; ++j)
        bfr[j] = *(const bf16x8*)(&Bs[cur][(wcol * 64 + j * 16 + r) * 32 + quad * 8]);
#pragma unroll
      for (int i = 0; i < 4; ++i)
#pragma unroll
        for (int j = 0; j < 4; ++j)
          acc[i][j] = __builtin_amdgcn_mfma_f32_16x16x32_bf16(af[i], bfr[j],
                                                              acc[i][j], 0, 0, 0);
      // one barrier per step: drains this step's stage (next buf ready) and
      // guarantees everyone finished reading cur before it's overwritten.
      __syncthreads();
      cur ^= 1;
    }

    // C/D layout: col = lane&15, row = quad*4 + reg.
    // pos fold: the unique (tile,j,r) with m == cid[b] owns d_logit[b,cid[b]]
    // -> plain store, no race. cid is 32KB, L2-resident after first touches.
    for (int i = 0; i < 4; ++i) {
      for (int reg = 0; reg < 4; ++reg) {
        int b = brow0 + wrow * 64 + i * 16 + quad * 4 + reg;
        int lab = cid[b];
        float s = 0.0f;
#pragma unroll
        for (int j = 0; j < 4; ++j) {
          int m = mrow0 + wcol * 64 + j * 16 + r;
          float v = acc[i][j][reg];
          if (m < M_N) s += __expf(v);
          if (m == lab) pos[b] = v;
        }
        s += __shfl_xor(s, 1);
        s += __shfl_xor(s, 2);
        s += __shfl_xor(s, 4);
        s += __shfl_xor(s, 8);
        if (r == 0) atomicAdd(den + b, s);
      }
    }
    return;
  }

  const int ord = blk - GEMM_TILES;   // 0..6399
  if (ord < CE_BLOCKS) {
    // ---- CE phase: backfills as GEMM retires; 20 waves/CU streaming ----
    ce_span(ord * 4 + wid, lq, lr, rowsum);
    return;
  }
  const int oo = ord - CE_BLOCKS;
  if (oo < OBJ_BLOCKS) {
    // ---- obj role (moved from A: fills B's idle tail, shrinks A by 32MB).
    int b = oo * 4 + wid;
    const float* vr = v_max + (size_t)b * D_N + lane * 8;
    const float* mr = mm + (size_t)b * D_N + lane * 8;
    f32x4 a0 = nt_load4(vr), a1 = nt_load4(vr + 4);   // single-use: nt
    f32x4 b0 = nt_load4(mr), b1 = nt_load4(mr + 4);
    float sv = a0.x*a0.x + a0.y*a0.y + a0.z*a0.z + a0.w*a0.w
             + a1.x*a1.x + a1.y*a1.y + a1.z*a1.z + a1.w*a1.w;
    float sm = b0.x*b0.x + b0.y*b0.y + b0.z*b0.z + b0.w*b0.w
             + b1.x*b1.x + b1.y*b1.y + b1.z*b1.z + b1.w*b1.w;
    float sd = a0.x*b0.x + a0.y*b0.y + a0.z*b0.z + a0.w*b0.w
             + a1.x*b1.x + a1.y*b1.y + a1.z*b1.z + a1.w*b1.w;
    for (int o = 1; o < 64; o <<= 1) {
      sv += __shfl_xor(sv, o);
      sm += __shfl_xor(sm, o);
      sd += __shfl_xor(sd, o);
    }
    if (lane == 0) {
      float dist = sd / (fmaxf(sqrtf(sv), 1e-8f) * fmaxf(sqrtf(sm), 1e-8f));
      obj[b] = 1.0f - dist;
    }
  }
  // remaining 180 blocks: idle, retire immediately.
}

// ---------------------------------------------------------------------------
// Kernel C: per-row losses -> acc[0..3], combine folded in via arrival
// counter. Only 32 blocks -> the device-scope fence here is cheap (R1
// measured); NEVER scale this pattern to thousands of blocks (R3 lesson:
// per-block device fences at grid scale collapse memory throughput 5x).
__global__ __launch_bounds__(256) void c_final_kernel(
    const float* __restrict__ den, const float* __restrict__ pos,
    const float* __restrict__ rowsum,
    const float* __restrict__ lq, const float* __restrict__ lr,
    const int* __restrict__ cid, const float* __restrict__ obj,
    float* __restrict__ acc, float* __restrict__ out) {
  int b = blockIdx.x * 256 + threadIdx.x;  // 32*256 == B_N exactly
  int lab = cid[b];
  float xq = lq[(size_t)b * M_N + lab];
  float xr = lr[(size_t)b * M_N + lab];
  float s_nce = logf(den[b]) - pos[b];
  float s_ceq = logf(rowsum[b]) - xq;
  float s_cer = logf(rowsum[B_N + b]) - xr;
  float s_obj = obj[b];
  for (int o = 1; o < 64; o <<= 1) {
    s_nce += __shfl_xor(s_nce, o);
    s_ceq += __shfl_xor(s_ceq, o);
    s_cer += __shfl_xor(s_cer, o);
    s_obj += __shfl_xor(s_obj, o);
  }
  __shared__ float red[4][4];
  int wid = threadIdx.x >> 6;
  if ((threadIdx.x & 63) == 0) {
    red[wid][0] = s_nce; red[wid][1] = s_ceq;
    red[wid][2] = s_cer; red[wid][3] = s_obj;
  }
  __syncthreads();
  if (threadIdx.x < 4) {
    float v = red[0][threadIdx.x] + red[1][threadIdx.x]
            + red[2][threadIdx.x] + red[3][threadIdx.x];
    atomicAdd(acc + threadIdx.x, v);
  }
  if (threadIdx.x == 0) {
    __threadfence();  // release: acc adds (lanes 0-3, same wave) visible first
    unsigned prev = atomicAdd((unsigned*)(acc + 4), 1u);
    if (prev == 31u) {  // last arriver: all 32 blocks' adds are visible
      float nce = atomicAdd(acc + 0, 0.0f) / (float)B_N;
      float ceq = atomicAdd(acc + 1, 0.0f) / (float)B_N;
      float cer = atomicAdd(acc + 2, 0.0f) / (float)B_N;
      float ob  = atomicAdd(acc + 3, 0.0f) / (float)B_N;
      float fusion = (cer + ob + nce) * (1.0f / 3.0f);
      out[0] = fusion + ceq;  // question_loss_weight = 1.0
      out[1] = fusion;
      out[2] = ceq;
    }
  }
}

// ---------------------------------------------------------------------------
extern "C" void kernel_launch(void* const* d_in, const int* in_sizes, int n_in,
                              void* d_out, int out_size, void* d_ws, size_t ws_size,
                              hipStream_t stream) {
  const float* mm_proj     = (const float*)d_in[0];
  const float* ans_emb     = (const float*)d_in[1];
  const float* v_max       = (const float*)d_in[2];
  const float* mm          = (const float*)d_in[3];
  const float* logits_q    = (const float*)d_in[4];
  const float* logits_rubi = (const float*)d_in[5];
  const int*   cid         = (const int*)d_in[6];
  float* out = (float*)d_out;

  // Workspace layout (16B-aligned):
  //   g_bf16 : 8192*512*2 = 8,388,608 B
  //   a_bf16 : 3200*512*2 = 3,276,800 B
  //   zero region: den[8192] | rowsum[16384] | acc[4] | cnt[4]  (kernel A)
  //   pos[8192] (fully written by GEMM epilogue), obj[8192] (B obj phase)
  char* ws = (char*)d_ws;
  __bf16* g = (__bf16*)ws;
  __bf16* a = (__bf16*)(ws + 8388608);
  float* den    = (float*)(ws + 8388608 + 3276800);
  float* rowsum = den + B_N;
  float* acc    = rowsum + 2 * B_N;   // acc[0..3], arrival counter at acc[4]
  float* pos    = acc + 8;
  float* obj    = pos + B_N;

  a_prep_kernel<<<A_BLOCKS, 256, 0, stream>>>(mm_proj, ans_emb, g, a, den);
  b_fused_kernel<<<B_BLOCKS, 256, 0, stream>>>(
      g, a, cid, v_max, mm, logits_q, logits_rubi, den, pos, rowsum, obj);
  c_final_kernel<<<B_N / 256, 256, 0, stream>>>(
      den, pos, rowsum, logits_q, logits_rubi, cid, obj, acc, out);
}